// Round 14
// baseline (65.951 us; speedup 1.0000x reference)
//
#pragma clang fp contract(off)
#include <hip/hip_runtime.h>
#include <hip/hip_bf16.h>

typedef unsigned long long u64;
typedef unsigned int u32;

#define NPTS   200000
#define MBOX   128
#define W64    3125      // NPTS / 64 exactly
#define W64C   3200      // padded row stride (u64 words)
#define SSAMP  256
#define AANCH  3
#define VOXELF 0.4f
#define PCSF   -75.2f
#define TILEW  9.375f    // 150/16
#define PADW   129       // LDS inter row stride (words): bank = (r+c)%32 -> conflict-free

// ---------------- Kernel Z: zero inter (64KB) + box/tile precompute (block 0) ----------------
__global__ __launch_bounds__(256) void kZ(uint4* __restrict__ interZ,
                                          const float* __restrict__ boxes,
                                          float* __restrict__ bpk,
                                          u64* __restrict__ tmask)
{
    int tid = threadIdx.x;
    interZ[blockIdx.x * 256 + tid] = make_uint4(0, 0, 0, 0);   // 16 blocks x 256 x 16B = 64KB
    if (blockIdx.x != 0) return;

    __shared__ float sbx[128], sby[128], srch[128];
    if (tid < 128) {
        float bx = boxes[tid*7+0], by = boxes[tid*7+1];
        float dx = boxes[tid*7+3], dy = boxes[tid*7+4];
        float hx = dx * 0.5f, hy = dy * 0.5f;
        float sq = hx*hx;
        sq = sq + hy*hy;
        float r = sqrtf(sq);                         // radii (GAMMA=1)
        float qx = floorf((bx - PCSF) / VOXELF);
        float qy = floorf((by - PCSF) / VOXELF);
        float rv = ceilf(r / VOXELF);                // rad_vox
        bpk[tid*8+0] = bx; bpk[tid*8+1] = by; bpk[tid*8+2] = r;  bpk[tid*8+3] = qx;
        bpk[tid*8+4] = qy; bpk[tid*8+5] = rv; bpk[tid*8+6] = 0.f; bpk[tid*8+7] = 0.f;
        sbx[tid] = bx; sby[tid] = by;
        srch[tid] = VOXELF * (rv + 2.0f);            // conservative reach (>=0.8m slack)
    }
    __syncthreads();
    int tx = tid & 15, ty = tid >> 4;
    float x0 = -75.0f + tx * TILEW, x1 = x0 + TILEW;
    float y0 = -75.0f + ty * TILEW, y1 = y0 + TILEW;
    u64 m0 = 0, m1 = 0;
    for (int m = 0; m < 128; ++m) {
        float rc = srch[m];
        bool c = (sbx[m] > x0 - rc) & (sbx[m] < x1 + rc) &
                 (sby[m] > y0 - rc) & (sby[m] < y1 + rc);
        if (m < 64) m0 |= ((u64)c) << m;
        else        m1 |= ((u64)c) << (m - 64);
    }
    tmask[tid*2]   = m0;
    tmask[tid*2+1] = m1;
}

// ---- Kernel A: tile-pruned masks -> full ballot rowbits write (no zero/atomicOr) + inter adds --
__global__ __launch_bounds__(256) void kA(const float* __restrict__ points,
                                          const float* __restrict__ bpk,
                                          const u64* __restrict__ tmask,
                                          u64* __restrict__ rowbits,
                                          u32* __restrict__ inter)
{
    __shared__ float4 sB4[128];     // {bx,by,r,qx}
    __shared__ float2 sB2[128];     // {qy,rv}
    __shared__ u64 sTM[512];
    int tid = threadIdx.x;
    if (tid < 128) {
        const float4* bp = (const float4*)bpk;
        float4 a = bp[tid*2];
        float4 b = bp[tid*2+1];
        sB4[tid] = a;
        sB2[tid] = make_float2(b.x, b.y);
    }
    sTM[tid]       = tmask[tid];
    sTM[tid + 256] = tmask[tid + 256];
    __syncthreads();

    int n = blockIdx.x * 256 + tid;
    if (n >= NPTS) return;                 // whole-wave exit only (NPTS % 64 == 0)
    float px = points[n*5+0], py = points[n*5+1];
    float cxn = floorf((px - PCSF) / VOXELF);
    float cyn = floorf((py - PCSF) / VOXELF);
    int tx = (int)floorf((px + 75.0f) * (1.0f / TILEW));
    int ty = (int)floorf((py + 75.0f) * (1.0f / TILEW));
    tx = tx < 0 ? 0 : (tx > 15 ? 15 : tx);
    ty = ty < 0 ? 0 : (ty > 15 ? 15 : ty);
    int tile = ty * 16 + tx;
    u64 c0 = sTM[tile*2], c1 = sTM[tile*2+1];
    u64 h0 = 0, h1 = 0;
    bool voxany = false;
    while (c0) {
        int m = __builtin_ctzll(c0); c0 &= c0 - 1;
        float4 bd = sB4[m]; float2 be = sB2[m];
        float ddx = px - bd.x, ddy = py - bd.y;
        float sq = ddx*ddx;
        sq = sq + ddy*ddy;
        float dis = sqrtf(sq);
        bool hit = (dis <= bd.z);
        bool vox = (fabsf(bd.w - cxn) < be.y) & (fabsf(be.x - cyn) < be.y);
        voxany |= vox;
        h0 |= ((u64)hit) << m;
    }
    while (c1) {
        int m = __builtin_ctzll(c1); c1 &= c1 - 1;
        float4 bd = sB4[m + 64]; float2 be = sB2[m + 64];
        float ddx = px - bd.x, ddy = py - bd.y;
        float sq = ddx*ddx;
        sq = sq + ddy*ddy;
        float dis = sqrtf(sq);
        bool hit = (dis <= bd.z);
        bool vox = (fabsf(bd.w - cxn) < be.y) & (fabsf(be.x - cyn) < be.y);
        voxany |= vox;
        h1 |= ((u64)hit) << m;
    }
    if (!voxany) { h0 = 0; h1 = 0; }       // point_mask = circle & vmask

    // ---- full-word ballot emission: wave owns word w; every rowbits[m][w] written ----
    int w = n >> 6, lane = n & 63;
    u64 mylo = 0, myhi = 0;
    for (int m = 0; m < 64; ++m) {
        u64 bal = __ballot(((h0 >> m) & 1ull) != 0);
        if (lane == m) mylo = bal;
    }
    for (int m = 0; m < 64; ++m) {
        u64 bal = __ballot(((h1 >> m) & 1ull) != 0);
        if (lane == m) myhi = bal;
    }
    rowbits[(size_t)lane * W64C + w]        = mylo;
    rowbits[(size_t)(lane + 64) * W64C + w] = myhi;

    // ---- sparse pairwise inter accumulation (atomicAdd on zeroed inter) ----
    if ((h0 | h1) == 0) return;
    u64 e = h0;
    while (e) {
        int m = __builtin_ctzll(e); e &= e - 1;
        u64 f = h0;
        while (f) { int j = __builtin_ctzll(f); f &= f - 1; atomicAdd(&inter[m*128 + j], 1u); }
        f = h1;
        while (f) { int j = __builtin_ctzll(f); f &= f - 1; atomicAdd(&inter[m*128 + 64 + j], 1u); }
    }
    e = h1;
    while (e) {
        int m = __builtin_ctzll(e); e &= e - 1;
        u64 f = h0;
        while (f) { int j = __builtin_ctzll(f); f &= f - 1; atomicAdd(&inter[(m+64)*128 + j], 1u); }
        f = h1;
        while (f) { int j = __builtin_ctzll(f); f &= f - 1; atomicAdd(&inter[(m+64)*128 + 64 + j], 1u); }
    }
}

// ---- Kernel D: LDS parallel argmax (2 thr/row) + static-skip greedy + compaction + gather ------
__global__ __launch_bounds__(256) void kD(const u32* __restrict__ inter,
                                          const int* __restrict__ labels,
                                          const int* __restrict__ pNA,
                                          const u64* __restrict__ rowbits,
                                          const float* __restrict__ points,
                                          float* __restrict__ out,
                                          float* __restrict__ out_anchor)
{
    __shared__ u32   sInt[128 * PADW];     // 66048 B, stride-129: conflict-free row reads
    __shared__ int   sLab[128];
    __shared__ u64   sKey[128][2];
    __shared__ float sMax[128];
    __shared__ int   sMidx[128];
    __shared__ int   sA[384];
    __shared__ int   sGof[128];
    __shared__ int   sCnt[128];
    __shared__ u64   sStat[2];
    __shared__ int   sNA;
    __shared__ u32   sl3[256], sl2[256], sl1[256];
    __shared__ u64   swt[13][4];
    int tid = threadIdx.x, bid = blockIdx.x;
    int lane = tid & 63, wv = tid >> 6;

    // ---- stage inter -> LDS (coalesced uint4 loads, scalar stores into padded rows) ----
    {
        const uint4* ip = (const uint4*)inter;
        #pragma unroll
        for (int k = 0; k < 16; ++k) {
            uint4 v = ip[k * 256 + tid];
            int e = (k * 256 + tid) * 4;
            int row = e >> 7, col = e & 127;
            u32* d = &sInt[row * PADW + col];
            d[0] = v.x; d[1] = v.y; d[2] = v.z; d[3] = v.w;
        }
    }
    if (tid < 128) {
        sLab[tid] = labels[tid];
        sA[tid] = -1; sA[tid + 128] = -1; sA[tid + 256] = -1;
    }
    if (tid == 255) sNA = *pNA;
    __syncthreads();

    // ---- parallel argmax: 2 threads per row, 64 serial cols each (no cross-lane chains) ----
    {
        int r = tid >> 1, h = tid & 1;
        u32 ci = sInt[r * PADW + r];
        int li = sLab[r];
        float best = 0.0f; int bj = h * 64;
        #pragma unroll 4
        for (int c = 0; c < 64; ++c) {
            int j = h * 64 + c;
            u32 I  = sInt[r * PADW + j];
            u32 cj = sInt[j * PADW + j];
            long un = (long)ci + (long)cj - (long)I;
            float v = 0.0f;
            if ((j != r) && (sLab[j] == li) && (un > 0))
                v = (float)I / fmaxf((float)un, 1.0f);
            if (v > best) { best = v; bj = j; }    // strict > : first index within half
        }
        sKey[r][h] = ((u64)__float_as_uint(best) << 32) | (u32)bj;
    }
    __syncthreads();
    if (tid < 128) {
        u64 k0 = sKey[tid][0], k1 = sKey[tid][1];
        u32 v0 = (u32)(k0 >> 32), v1 = (u32)(k1 >> 32);
        u64 kk = (v1 > v0) ? k1 : k0;              // tie -> lower half (smaller j)
        sMax[tid]  = __uint_as_float((u32)(kk >> 32));
        sMidx[tid] = (int)(kk & 0xffffffffu);
    }
    __syncthreads();

    // ---- static-no-join bitmask via wave-0 ballots: static <=> mmax<=0.5 || midx>=i ----
    if (wv == 0) {
        bool st1 = (sMax[lane] <= 0.5f)      || (sMidx[lane] >= lane);
        bool st2 = (sMax[lane + 64] <= 0.5f) || (sMidx[lane + 64] >= lane + 64);
        u64 b1 = __ballot(st1);
        u64 b2 = __ballot(st2);
        if (lane == 0) { sStat[0] = b1; sStat[1] = b2; }
    }
    __syncthreads();
    // ---- serial greedy: thread 0; static iters write-only, candidates pay LDS reads ----
    if (tid == 0) {
        int NA = sNA;
        u64 st0 = sStat[0], st1 = sStat[1];
        int ng = 0;
        for (int i = 0; i < 128; ++i) {
            bool isStatic = (i < 64) ? ((st0 >> i) & 1ull) : ((st1 >> (i - 64)) & 1ull);
            if (isStatic) {
                sA[ng * AANCH] = i;
                sGof[i] = ng;
                sCnt[ng] = 1;
                ng++;
            } else {
                int j  = sMidx[i];
                int gj = sGof[j];
                int gc = sCnt[gj];
                if (gc < NA) {
                    sA[gj * AANCH + gc] = i;
                    sGof[i] = gj;
                    sCnt[gj] = gc + 1;
                } else {
                    sA[ng * AANCH] = i;
                    sGof[i] = ng;
                    sCnt[ng] = 1;
                    ng++;
                }
            }
        }
    }
    __syncthreads();
    if (bid == 0) {
        for (int t = tid; t < 384; t += 256)
            out_anchor[t] = (float)sA[t];          // int32 ref chunk read back as f32 values
    }

    // ---- own-group compaction: prefetch + 13 independent wave scans + emit ----
    int g = bid;
    float* outg = out + (size_t)g * SSAMP * 5;
    int a0 = sA[g*3+0], a1 = sA[g*3+1], a2 = sA[g*3+2];
    if (a0 < 0) {                                  // invalid group -> all zeros (uniform exit)
        for (int t = tid; t < SSAMP * 5; t += 256) outg[t] = 0.0f;
        return;
    }
    bool vB = (a1 >= 0), vC = (a2 >= 0);
    const u64* rA = rowbits + (size_t)a0 * W64C;
    const u64* rB = rowbits + (size_t)(vB ? a1 : 0) * W64C;
    const u64* rC = rowbits + (size_t)(vC ? a2 : 0) * W64C;
    const u64 M21 = (1ull << 21) - 1;

    u64 va[13], vb[13], vc[13];
    #pragma unroll
    for (int k = 0; k < 13; ++k) {
        int w = k * 256 + tid;
        bool inr = (w < W64);
        va[k] = inr ? rA[w] : 0ull;
        vb[k] = (inr && vB) ? rB[w] : 0ull;
        vc[k] = (inr && vC) ? rC[w] : 0ull;
    }
    u64 exl[13];
    #pragma unroll
    for (int k = 0; k < 13; ++k) {
        u64 a = va[k], b = vb[k], c = vc[k];
        u64 m3 = a & b & c;
        u64 any2 = (a & b) | (a & c) | (b & c);
        u64 m2 = any2 & ~m3;
        u64 m1 = (a | b | c) & ~any2;
        u64 own = ((u64)__popcll(m3) << 42) | ((u64)__popcll(m2) << 21) | (u64)__popcll(m1);
        u64 p = own;
        #pragma unroll
        for (int d = 1; d < 64; d <<= 1) {
            u64 t = __shfl_up(p, d);
            if (lane >= d) p += t;
        }
        if (lane == 63) swt[k][wv] = p;
        exl[k] = p - own;
    }
    __syncthreads();
    u64 base = 0;
    #pragma unroll
    for (int k = 0; k < 13; ++k) {
        u64 off = base + exl[k];
        for (int w2 = 0; w2 < wv; ++w2) off += swt[k][w2];
        u64 a = va[k], b = vb[k], c = vc[k];
        u64 m3 = a & b & c;
        u64 any2 = (a & b) | (a & c) | (b & c);
        u64 m2 = any2 & ~m3;
        u64 m1 = (a | b | c) & ~any2;
        u32 e3 = (u32)(off >> 42);
        u32 e2 = (u32)((off >> 21) & M21);
        u32 e1 = (u32)(off & M21);
        int nb = k * 256 * 64 + tid * 64;
        u64 mm = m3; u32 o = e3;
        while (mm) { int b2 = __builtin_ctzll(mm); mm &= mm - 1; if (o < 256) sl3[o] = nb + b2; o++; }
        mm = m2; o = e2;
        while (mm) { int b2 = __builtin_ctzll(mm); mm &= mm - 1; if (o < 256) sl2[o] = nb + b2; o++; }
        mm = m1; o = e1;
        while (mm) { int b2 = __builtin_ctzll(mm); mm &= mm - 1; if (o < 256) sl1[o] = nb + b2; o++; }
        base += swt[k][0] + swt[k][1] + swt[k][2] + swt[k][3];
    }
    __syncthreads();
    u32 t3 = (u32)(base >> 42), t2c = (u32)((base >> 21) & M21), t1 = (u32)(base & M21);
    u32 s = (u32)tid;
    int n = -1;
    if (s < t3)                  n = (int)sl3[s];
    else if (s < t3 + t2c)       n = (int)sl2[s - t3];
    else if (s < t3 + t2c + t1)  n = (int)sl1[s - t3 - t2c];
    float v0=0.f, v1=0.f, v2=0.f, v3=0.f, v4=0.f;
    if (n >= 0) {
        const float* pp = points + (size_t)n * 5;
        v0 = pp[0]; v1 = pp[1]; v2 = pp[2]; v3 = pp[3]; v4 = pp[4];
    }
    outg[s*5+0] = v0; outg[s*5+1] = v1; outg[s*5+2] = v2;
    outg[s*5+3] = v3; outg[s*5+4] = v4;
}

extern "C" void kernel_launch(void* const* d_in, const int* in_sizes, int n_in,
                              void* d_out, int out_size, void* d_ws, size_t ws_size,
                              hipStream_t stream)
{
    const float* points = (const float*)d_in[0];
    const float* boxes  = (const float*)d_in[1];
    const int*   labels = (const int*)d_in[2];
    const int*   pNA    = (const int*)d_in[4];
    float* out = (float*)d_out;
    char* ws = (char*)d_ws;

    size_t rowsz = (size_t)MBOX * W64C * 8;                    // 3,276,800 B (never zeroed now)
    u64*  rowbits = (u64*)ws;
    u32*  inter   = (u32*)(ws + rowsz);                        // 65,536 B (zeroed by kZ)
    float* bpk    = (float*)(ws + rowsz + 65536);              // 4,096 B
    u64*  tmask   = (u64*)(ws + rowsz + 65536 + 4096);         // 4,096 B

    float* out_anchor = out + (size_t)MBOX * SSAMP * 5;        // second output chunk

    kZ<<<16, 256, 0, stream>>>((uint4*)inter, boxes, bpk, tmask);
    kA<<<(NPTS + 255) / 256, 256, 0, stream>>>(points, bpk, tmask, rowbits, inter);
    kD<<<MBOX, 256, 0, stream>>>(inter, labels, pNA, rowbits, points, out, out_anchor);
}

// Round 15
// 49.565 us; speedup vs baseline: 1.3306x; 1.3306x over previous
//
#pragma clang fp contract(off)
#include <hip/hip_runtime.h>
#include <hip/hip_bf16.h>

typedef unsigned long long u64;
typedef unsigned int u32;

#define NPTS   200000
#define MBOX   128
#define W64    3125      // NPTS / 64 exactly
#define W64C   3200      // padded row stride (u64 words)
#define SSAMP  256
#define AANCH  3
#define VOXELF 0.4f
#define PCSF   -75.2f
#define TILEW  9.375f    // 150/16
#define NCHK   7         // 7 chunks x 512 threads = 3584 >= 3125

// ---------------- Kernel ZP: zero rowbits+inter (all blocks) + box/tile precompute (block 0) ----
__global__ __launch_bounds__(256) void kZP(uint4* __restrict__ zbase,
                                           const float* __restrict__ boxes,
                                           float* __restrict__ bpk,
                                           u64* __restrict__ tmask)
{
    int tid = threadIdx.x;
    zbase[(size_t)blockIdx.x * 256 + tid] = make_uint4(0, 0, 0, 0);
    if (blockIdx.x != 0) return;

    __shared__ float sbx[128], sby[128], srch[128];
    if (tid < 128) {
        float bx = boxes[tid*7+0], by = boxes[tid*7+1];
        float dx = boxes[tid*7+3], dy = boxes[tid*7+4];
        float hx = dx * 0.5f, hy = dy * 0.5f;
        float sq = hx*hx;
        sq = sq + hy*hy;
        float r = sqrtf(sq);                         // radii (GAMMA=1)
        float qx = floorf((bx - PCSF) / VOXELF);
        float qy = floorf((by - PCSF) / VOXELF);
        float rv = ceilf(r / VOXELF);                // rad_vox
        bpk[tid*8+0] = bx; bpk[tid*8+1] = by; bpk[tid*8+2] = r;  bpk[tid*8+3] = qx;
        bpk[tid*8+4] = qy; bpk[tid*8+5] = rv; bpk[tid*8+6] = 0.f; bpk[tid*8+7] = 0.f;
        sbx[tid] = bx; sby[tid] = by;
        srch[tid] = VOXELF * (rv + 2.0f);            // conservative reach (>=0.8m slack)
    }
    __syncthreads();
    int tx = tid & 15, ty = tid >> 4;
    float x0 = -75.0f + tx * TILEW, x1 = x0 + TILEW;
    float y0 = -75.0f + ty * TILEW, y1 = y0 + TILEW;
    u64 m0 = 0, m1 = 0;
    for (int m = 0; m < 128; ++m) {
        float rc = srch[m];
        bool c = (sbx[m] > x0 - rc) & (sbx[m] < x1 + rc) &
                 (sby[m] > y0 - rc) & (sby[m] < y1 + rc);
        if (m < 64) m0 |= ((u64)c) << m;
        else        m1 |= ((u64)c) << (m - 64);
    }
    tmask[tid*2]   = m0;
    tmask[tid*2+1] = m1;
}

// ---------------- Kernel A: tile-pruned masks -> sparse atomicOr rowbits + atomicAdd inter --
__global__ __launch_bounds__(256) void kA(const float* __restrict__ points,
                                          const float* __restrict__ bpk,
                                          const u64* __restrict__ tmask,
                                          u64* __restrict__ rowbits,
                                          u32* __restrict__ inter)
{
    __shared__ float4 sB4[128];     // {bx,by,r,qx}
    __shared__ float2 sB2[128];     // {qy,rv}
    __shared__ u64 sTM[512];
    int tid = threadIdx.x;
    if (tid < 128) {
        const float4* bp = (const float4*)bpk;
        float4 a = bp[tid*2];
        float4 b = bp[tid*2+1];
        sB4[tid] = a;
        sB2[tid] = make_float2(b.x, b.y);
    }
    sTM[tid]       = tmask[tid];
    sTM[tid + 256] = tmask[tid + 256];
    __syncthreads();

    int n = blockIdx.x * 256 + tid;
    if (n >= NPTS) return;
    float px = points[n*5+0], py = points[n*5+1];
    float cxn = floorf((px - PCSF) / VOXELF);
    float cyn = floorf((py - PCSF) / VOXELF);
    int tx = (int)floorf((px + 75.0f) * (1.0f / TILEW));
    int ty = (int)floorf((py + 75.0f) * (1.0f / TILEW));
    tx = tx < 0 ? 0 : (tx > 15 ? 15 : tx);
    ty = ty < 0 ? 0 : (ty > 15 ? 15 : ty);
    int tile = ty * 16 + tx;
    u64 c0 = sTM[tile*2], c1 = sTM[tile*2+1];
    u64 h0 = 0, h1 = 0;
    bool voxany = false;
    while (c0) {
        int m = __builtin_ctzll(c0); c0 &= c0 - 1;
        float4 bd = sB4[m]; float2 be = sB2[m];
        float ddx = px - bd.x, ddy = py - bd.y;
        float sq = ddx*ddx;
        sq = sq + ddy*ddy;
        float dis = sqrtf(sq);
        bool hit = (dis <= bd.z);
        bool vox = (fabsf(bd.w - cxn) < be.y) & (fabsf(be.x - cyn) < be.y);
        voxany |= vox;
        h0 |= ((u64)hit) << m;
    }
    while (c1) {
        int m = __builtin_ctzll(c1); c1 &= c1 - 1;
        float4 bd = sB4[m + 64]; float2 be = sB2[m + 64];
        float ddx = px - bd.x, ddy = py - bd.y;
        float sq = ddx*ddx;
        sq = sq + ddy*ddy;
        float dis = sqrtf(sq);
        bool hit = (dis <= bd.z);
        bool vox = (fabsf(bd.w - cxn) < be.y) & (fabsf(be.x - cyn) < be.y);
        voxany |= vox;
        h1 |= ((u64)hit) << m;
    }
    if (!voxany) { h0 = 0; h1 = 0; }       // point_mask = circle & vmask
    if ((h0 | h1) == 0) return;

    int w = n >> 6, lane = n & 63;
    u64 lanebit = 1ull << lane;
    u64 e = h0;
    while (e) {
        int m = __builtin_ctzll(e); e &= e - 1;
        atomicOr(&rowbits[(size_t)m * W64C + w], lanebit);
        u64 f = h0;
        while (f) { int j = __builtin_ctzll(f); f &= f - 1; atomicAdd(&inter[m*128 + j], 1u); }
        f = h1;
        while (f) { int j = __builtin_ctzll(f); f &= f - 1; atomicAdd(&inter[m*128 + 64 + j], 1u); }
    }
    e = h1;
    while (e) {
        int m = __builtin_ctzll(e); e &= e - 1;
        atomicOr(&rowbits[(size_t)(m + 64) * W64C + w], lanebit);
        u64 f = h0;
        while (f) { int j = __builtin_ctzll(f); f &= f - 1; atomicAdd(&inter[(m+64)*128 + j], 1u); }
        f = h1;
        while (f) { int j = __builtin_ctzll(f); f &= f - 1; atomicAdd(&inter[(m+64)*128 + 64 + j], 1u); }
    }
}

// ---------------- Kernel C1: per-row argmax — f32 butterfly + ballot tie-break ----------------
__global__ __launch_bounds__(64) void kC1(const u32* __restrict__ inter,
                                          const int* __restrict__ labels,
                                          float* __restrict__ mmaxW,
                                          int* __restrict__ midxW)
{
    int i = blockIdx.x, lane = threadIdx.x;
    int j1 = lane, j2 = lane + 64;
    u32 ci = inter[i * 128 + i];                 // uniform
    int li = labels[i];
    u32 I1 = inter[i * 128 + j1];                // coalesced
    u32 I2 = inter[i * 128 + j2];
    u32 c1 = inter[j1 * 128 + j1];               // strided diag, L2-hot
    u32 c2 = inter[j2 * 128 + j2];
    int l1 = labels[j1], l2 = labels[j2];
    long un1 = (long)ci + (long)c1 - (long)I1;
    long un2 = (long)ci + (long)c2 - (long)I2;
    float v1 = 0.0f, v2 = 0.0f;
    if ((j1 != i) && (l1 == li) && (un1 > 0))
        v1 = (float)I1 / fmaxf((float)un1, 1.0f);
    if ((j2 != i) && (l2 == li) && (un2 > 0))
        v2 = (float)I2 / fmaxf((float)un2, 1.0f);
    float vm = fmaxf(v1, v2);
    #pragma unroll
    for (int d = 1; d < 64; d <<= 1)
        vm = fmaxf(vm, __shfl_xor(vm, d));
    u64 b1 = __ballot(v1 == vm);
    u64 b2 = __ballot(v2 == vm);
    int j = b1 ? __builtin_ctzll(b1) : 64 + __builtin_ctzll(b2);   // first-index argmax
    if (lane == 0) { mmaxW[i] = vm; midxW[i] = j; }
}

// ---- Kernel D: static-skip greedy (redundant per block) + 512-thread compaction + gather -------
__global__ __launch_bounds__(512) void kD(const float* __restrict__ mmaxW,
                                          const int* __restrict__ midxW,
                                          const int* __restrict__ pNA,
                                          const u64* __restrict__ rowbits,
                                          const float* __restrict__ points,
                                          float* __restrict__ out,
                                          float* __restrict__ out_anchor)
{
    __shared__ float sMax[128];
    __shared__ int   sMidx[128];
    __shared__ int   sA[384];
    __shared__ int   sGof[128];
    __shared__ int   sCnt[128];
    __shared__ u64   sStat[2];
    __shared__ int   sNA;
    __shared__ u32   sl3[256], sl2[256], sl1[256];
    __shared__ u64   swt[NCHK][8];
    int tid = threadIdx.x, bid = blockIdx.x;
    int lane = tid & 63, wv = tid >> 6;     // 8 waves

    if (tid < 128) {
        sMax[tid]  = mmaxW[tid];
        sMidx[tid] = midxW[tid];
        sA[tid] = -1; sA[tid + 128] = -1; sA[tid + 256] = -1;
    }
    if (tid == 255) sNA = *pNA;
    __syncthreads();
    // ---- static-no-join bitmask via wave-0 ballots: static <=> mmax<=0.5 || midx>=i ----
    if (wv == 0) {
        bool st1 = (sMax[lane] <= 0.5f)      || (sMidx[lane] >= lane);
        bool st2 = (sMax[lane + 64] <= 0.5f) || (sMidx[lane + 64] >= lane + 64);
        u64 b1 = __ballot(st1);
        u64 b2 = __ballot(st2);
        if (lane == 0) { sStat[0] = b1; sStat[1] = b2; }
    }
    __syncthreads();
    // ---- serial greedy: thread 0; static iters write-only, candidates pay LDS reads ----
    if (tid == 0) {
        int NA = sNA;
        u64 st0 = sStat[0], st1 = sStat[1];
        int ng = 0;
        for (int i = 0; i < 128; ++i) {
            bool isStatic = (i < 64) ? ((st0 >> i) & 1ull) : ((st1 >> (i - 64)) & 1ull);
            if (isStatic) {
                sA[ng * AANCH] = i;      // ts = 0
                sGof[i] = ng;
                sCnt[ng] = 1;
                ng++;
            } else {
                int j  = sMidx[i];       // chained LDS reads (candidates only)
                int gj = sGof[j];
                int gc = sCnt[gj];
                if (gc < NA) {
                    sA[gj * AANCH + gc] = i;
                    sGof[i] = gj;
                    sCnt[gj] = gc + 1;
                } else {
                    sA[ng * AANCH] = i;
                    sGof[i] = ng;
                    sCnt[ng] = 1;
                    ng++;
                }
            }
        }
    }
    __syncthreads();
    if (bid == 0) {
        for (int t = tid; t < 384; t += 512)
            out_anchor[t] = (float)sA[t];      // int32 ref chunk read back as f32 values
    }

    // ---- own-group compaction: prefetch + 7 independent wave scans + emit ----
    int g = bid;
    float* outg = out + (size_t)g * SSAMP * 5;
    int a0 = sA[g*3+0], a1 = sA[g*3+1], a2 = sA[g*3+2];
    if (a0 < 0) {                              // invalid group -> all zeros (block-uniform exit)
        for (int t = tid; t < SSAMP * 5; t += 512) outg[t] = 0.0f;
        return;
    }
    bool vB = (a1 >= 0), vC = (a2 >= 0);
    const u64* rA = rowbits + (size_t)a0 * W64C;
    const u64* rB = rowbits + (size_t)(vB ? a1 : 0) * W64C;
    const u64* rC = rowbits + (size_t)(vC ? a2 : 0) * W64C;
    const u64 M21 = (1ull << 21) - 1;

    u64 va[NCHK], vb[NCHK], vc[NCHK];
    #pragma unroll
    for (int k = 0; k < NCHK; ++k) {
        int w = k * 512 + tid;
        bool inr = (w < W64);
        va[k] = inr ? rA[w] : 0ull;
        vb[k] = (inr && vB) ? rB[w] : 0ull;
        vc[k] = (inr && vC) ? rC[w] : 0ull;
    }
    u64 exl[NCHK];
    #pragma unroll
    for (int k = 0; k < NCHK; ++k) {
        u64 a = va[k], b = vb[k], c = vc[k];
        u64 m3 = a & b & c;
        u64 any2 = (a & b) | (a & c) | (b & c);
        u64 m2 = any2 & ~m3;
        u64 m1 = (a | b | c) & ~any2;
        u64 own = ((u64)__popcll(m3) << 42) | ((u64)__popcll(m2) << 21) | (u64)__popcll(m1);
        u64 p = own;
        #pragma unroll
        for (int d = 1; d < 64; d <<= 1) {
            u64 t = __shfl_up(p, d);
            if (lane >= d) p += t;
        }
        if (lane == 63) swt[k][wv] = p;
        exl[k] = p - own;
    }
    __syncthreads();
    u64 base = 0;
    #pragma unroll
    for (int k = 0; k < NCHK; ++k) {
        u64 off = base + exl[k];
        for (int w2 = 0; w2 < wv; ++w2) off += swt[k][w2];
        u64 a = va[k], b = vb[k], c = vc[k];
        u64 m3 = a & b & c;
        u64 any2 = (a & b) | (a & c) | (b & c);
        u64 m2 = any2 & ~m3;
        u64 m1 = (a | b | c) & ~any2;
        u32 e3 = (u32)(off >> 42);
        u32 e2 = (u32)((off >> 21) & M21);
        u32 e1 = (u32)(off & M21);
        int nb = (k * 512 + tid) * 64;
        u64 mm = m3; u32 o = e3;
        while (mm) { int b2 = __builtin_ctzll(mm); mm &= mm - 1; if (o < 256) sl3[o] = nb + b2; o++; }
        mm = m2; o = e2;
        while (mm) { int b2 = __builtin_ctzll(mm); mm &= mm - 1; if (o < 256) sl2[o] = nb + b2; o++; }
        mm = m1; o = e1;
        while (mm) { int b2 = __builtin_ctzll(mm); mm &= mm - 1; if (o < 256) sl1[o] = nb + b2; o++; }
        u64 wt = swt[k][0];
        #pragma unroll
        for (int w2 = 1; w2 < 8; ++w2) wt += swt[k][w2];
        base += wt;
    }
    __syncthreads();
    if (tid < 256) {
        u32 t3 = (u32)(base >> 42), t2c = (u32)((base >> 21) & M21), t1 = (u32)(base & M21);
        u32 s = (u32)tid;
        int n = -1;
        if (s < t3)                  n = (int)sl3[s];
        else if (s < t3 + t2c)       n = (int)sl2[s - t3];
        else if (s < t3 + t2c + t1)  n = (int)sl1[s - t3 - t2c];
        float v0=0.f, v1=0.f, v2=0.f, v3=0.f, v4=0.f;
        if (n >= 0) {
            const float* pp = points + (size_t)n * 5;
            float4 p4 = *(const float4*)pp;    // points rows are 20B, 4B-aligned reads
            v0 = p4.x; v1 = p4.y; v2 = p4.z; v3 = p4.w; v4 = pp[4];
        }
        outg[s*5+0] = v0; outg[s*5+1] = v1; outg[s*5+2] = v2;
        outg[s*5+3] = v3; outg[s*5+4] = v4;
    }
}

extern "C" void kernel_launch(void* const* d_in, const int* in_sizes, int n_in,
                              void* d_out, int out_size, void* d_ws, size_t ws_size,
                              hipStream_t stream)
{
    const float* points = (const float*)d_in[0];
    const float* boxes  = (const float*)d_in[1];
    const int*   labels = (const int*)d_in[2];
    const int*   pNA    = (const int*)d_in[4];
    float* out = (float*)d_out;
    char* ws = (char*)d_ws;

    size_t rowsz = (size_t)MBOX * W64C * 8;                    // 3,276,800 B
    u64*  rowbits = (u64*)ws;
    u32*  inter   = (u32*)(ws + rowsz);                        // 65,536 B (contiguous zero region)
    float* bpk    = (float*)(ws + rowsz + 65536);              // 4,096 B
    u64*  tmask   = (u64*)(ws + rowsz + 65536 + 4096);         // 4,096 B
    float* mmaxW  = (float*)(ws + rowsz + 65536 + 8192);       // 512 B
    int*   midxW  = (int*)(ws + rowsz + 65536 + 8704);         // 512 B

    float* out_anchor = out + (size_t)MBOX * SSAMP * 5;        // second output chunk

    kZP<<<816, 256, 0, stream>>>((uint4*)ws, boxes, bpk, tmask);
    kA<<<(NPTS + 255) / 256, 256, 0, stream>>>(points, bpk, tmask, rowbits, inter);
    kC1<<<MBOX, 64, 0, stream>>>(inter, labels, mmaxW, midxW);
    kD<<<MBOX, 512, 0, stream>>>(mmaxW, midxW, pNA, rowbits, points, out, out_anchor);
}